// Round 1
// baseline (1869.320 us; speedup 1.0000x reference)
//
#include <hip/hip_runtime.h>
#include <hip/hip_bf16.h>
#include <cstdint>
#include <cstddef>

// ---------------------------------------------------------------------------
// GPT-2-small forward on MI355X. bf16 MFMA GEMMs (f32 accum), f32 residual
// stream. All weights repacked to bf16 TRANSPOSED ([N][K]) each launch so
// GEMM B-fragments are contiguous ds_read_b128 (m92 "B^T" pattern).
// ---------------------------------------------------------------------------

typedef __bf16 bf16x8 __attribute__((ext_vector_type(8)));
typedef float  f32x4  __attribute__((ext_vector_type(4)));

#define MFMA16(a, b, c) __builtin_amdgcn_mfma_f32_16x16x32_bf16((a), (b), (c), 0, 0, 0)

__device__ __forceinline__ void g2l16(const void* g, void* l) {
    __builtin_amdgcn_global_load_lds(
        (const __attribute__((address_space(1))) void*)g,
        (__attribute__((address_space(3))) void*)l, 16, 0, 0);
}

// ---------------------------------------------------------------------------
// Weight repack: f32 [K,N] (row-major) -> bf16 [N,K] (row-major), 32x32 tiles.
// ---------------------------------------------------------------------------
__global__ __launch_bounds__(256) void transpose_cvt(
    const float* __restrict__ src, __bf16* __restrict__ dst,
    int K, int N, int nNT)
{
    const float* s = src + (size_t)blockIdx.y * K * N;
    __bf16*      d = dst + (size_t)blockIdx.y * K * N;
    int kt = blockIdx.x / nNT, nt = blockIdx.x % nNT;
    int k0 = kt * 32, n0 = nt * 32;
    __shared__ float t[32][33];
    int tx = threadIdx.x & 31, ty = threadIdx.x >> 5;
#pragma unroll
    for (int i = 0; i < 4; i++)
        t[ty + i * 8][tx] = s[(size_t)(k0 + ty + i * 8) * N + n0 + tx];
    __syncthreads();
#pragma unroll
    for (int i = 0; i < 4; i++)
        d[(size_t)(n0 + ty + i * 8) * K + k0 + tx] = (__bf16)t[tx][ty + i * 8];
}

// QKV gather-repack: Wq/Wk/Wv [L,H,768,64] f32 -> Wqkv_t [L][2304][768] bf16,
// where dst row c = m*768 + h*64 + s holds column (h,s) of W{m}[l] over d.
__global__ __launch_bounds__(256) void repack_qkv(
    const float* __restrict__ Wq, const float* __restrict__ Wk,
    const float* __restrict__ Wv, __bf16* __restrict__ dst)
{
    int l = blockIdx.z;
    int m = blockIdx.y / 12, h = blockIdx.y % 12;
    int kt = blockIdx.x / 2, nt = blockIdx.x % 2;   // K=768: 24 tiles, N=64: 2
    const float* W = (m == 0 ? Wq : (m == 1 ? Wk : Wv)) + ((size_t)(l * 12 + h)) * 768 * 64;
    __bf16* d = dst + (size_t)l * 2304 * 768 + (size_t)(m * 768 + h * 64) * 768;
    int k0 = kt * 32, n0 = nt * 32;
    __shared__ float t[32][33];
    int tx = threadIdx.x & 31, ty = threadIdx.x >> 5;
#pragma unroll
    for (int i = 0; i < 4; i++)
        t[ty + i * 8][tx] = W[(size_t)(k0 + ty + i * 8) * 64 + n0 + tx];
    __syncthreads();
#pragma unroll
    for (int i = 0; i < 4; i++)
        d[(size_t)(n0 + ty + i * 8) * 768 + k0 + tx] = (__bf16)t[tx][ty + i * 8];
}

// ---------------------------------------------------------------------------
// Embedding: x[t,:] = tok_emb[idx[t],:] + pos_emb[t%1024,:]   (f32)
// ---------------------------------------------------------------------------
__global__ __launch_bounds__(256) void embed_kernel(
    const int* __restrict__ idx, const float* __restrict__ tok,
    const float* __restrict__ pos, float* __restrict__ x)
{
    const int t = blockIdx.x, tid = threadIdx.x;
    int id = idx[t];
    const float* te = tok + (size_t)id * 768;
    const float* pe = pos + (size_t)(t & 1023) * 768;
    float* xr = x + (size_t)t * 768;
    xr[tid]       = te[tid]       + pe[tid];
    xr[tid + 256] = te[tid + 256] + pe[tid + 256];
    xr[tid + 512] = te[tid + 512] + pe[tid + 512];
}

// ---------------------------------------------------------------------------
// LayerNorm: f32 in -> bf16 out. One 256-thread block per row (768 elems).
// ---------------------------------------------------------------------------
__global__ __launch_bounds__(256) void ln_kernel(
    const float* __restrict__ x, const float* __restrict__ g,
    const float* __restrict__ bb, __bf16* __restrict__ out)
{
    const int row = blockIdx.x, tid = threadIdx.x;
    const float* xr = x + (size_t)row * 768;
    float v0 = xr[tid], v1 = xr[tid + 256], v2 = xr[tid + 512];
    float s  = v0 + v1 + v2;
    float s2 = v0 * v0 + v1 * v1 + v2 * v2;
#pragma unroll
    for (int d = 1; d < 64; d <<= 1) {
        s  += __shfl_xor(s, d);
        s2 += __shfl_xor(s2, d);
    }
    __shared__ float sb[8];
    int w = tid >> 6, l = tid & 63;
    if (l == 0) { sb[w] = s; sb[4 + w] = s2; }
    __syncthreads();
    s  = sb[0] + sb[1] + sb[2] + sb[3];
    s2 = sb[4] + sb[5] + sb[6] + sb[7];
    float mean = s * (1.f / 768.f);
    float var  = s2 * (1.f / 768.f) - mean * mean;
    float rstd = rsqrtf(var + 1e-5f);
    __bf16* orow = out + (size_t)row * 768;
    orow[tid]       = (__bf16)((v0 - mean) * rstd * g[tid]       + bb[tid]);
    orow[tid + 256] = (__bf16)((v1 - mean) * rstd * g[tid + 256] + bb[tid + 256]);
    orow[tid + 512] = (__bf16)((v2 - mean) * rstd * g[tid + 512] + bb[tid + 512]);
}

// ---------------------------------------------------------------------------
// GEMM (m97 structure): C[M,N] = A[M,K]@B[K,N], A bf16 row-major (lda=K),
// B supplied TRANSPOSED bf16 [N][K] (ld=K). 128x128 tile, BK=32, 4 waves 2x2,
// each wave 64x64 via 4x4 mfma_f32_16x16x32_bf16 frags. global_load_lds w=16.
// Epilogue: +bias, +f32 residual, relu, f32 or bf16 out.
// ---------------------------------------------------------------------------
template <int RELU, int BIAS, int RES, int OBF16>
__global__ __launch_bounds__(256, 2) void gemm_bt(
    const __bf16* __restrict__ A, const __bf16* __restrict__ Bt,
    const float* __restrict__ bias, const float* __restrict__ res,
    void* __restrict__ Cout, int M, int N, int K)
{
    __shared__ __bf16 Al[128 * 32];
    __shared__ __bf16 Bl[128 * 32];
    const int tid = threadIdx.x;
    const int w = tid >> 6, l = tid & 63, lr = l & 15, lg = l >> 4;
    const int wr = w >> 1, wc = w & 1;
    const int m0 = blockIdx.y * 128, n0 = blockIdx.x * 128;

    f32x4 acc[4][4];
#pragma unroll
    for (int i = 0; i < 4; i++)
#pragma unroll
        for (int j = 0; j < 4; j++) acc[i][j] = (f32x4){0.f, 0.f, 0.f, 0.f};

    // staging chunk ids: c = i*256 + tid ; chunk -> row c>>2, 8-elem col (c&3)*8
    const int c0 = tid, c1 = 256 + tid;
    const __bf16* ag0 = A  + (size_t)(m0 + (c0 >> 2)) * K + (c0 & 3) * 8;
    const __bf16* ag1 = A  + (size_t)(m0 + (c1 >> 2)) * K + (c1 & 3) * 8;
    const __bf16* bg0 = Bt + (size_t)(n0 + (c0 >> 2)) * K + (c0 & 3) * 8;
    const __bf16* bg1 = Bt + (size_t)(n0 + (c1 >> 2)) * K + (c1 & 3) * 8;
    char* al0 = (char*)Al + (w * 64) * 16;
    char* al1 = (char*)Al + (256 + w * 64) * 16;
    char* bl0 = (char*)Bl + (w * 64) * 16;
    char* bl1 = (char*)Bl + (256 + w * 64) * 16;

    for (int k0 = 0; k0 < K; k0 += 32) {
        __syncthreads();
        g2l16(ag0 + k0, al0);
        g2l16(ag1 + k0, al1);
        g2l16(bg0 + k0, bl0);
        g2l16(bg1 + k0, bl1);
        __syncthreads();
        bf16x8 af[4], bfv[4];
#pragma unroll
        for (int i = 0; i < 4; i++) {
            af[i]  = *(const bf16x8*)&Al[(wr * 64 + i * 16 + lr) * 32 + lg * 8];
            bfv[i] = *(const bf16x8*)&Bl[(wc * 64 + i * 16 + lr) * 32 + lg * 8];
        }
#pragma unroll
        for (int i = 0; i < 4; i++)
#pragma unroll
            for (int j = 0; j < 4; j++)
                acc[i][j] = MFMA16(af[i], bfv[j], acc[i][j]);
    }

    // epilogue; C/D layout: col = lane&15, row = (lane>>4)*4 + r  [m89]
#pragma unroll
    for (int i = 0; i < 4; i++) {
        int row = m0 + wr * 64 + i * 16 + lg * 4;
#pragma unroll
        for (int j = 0; j < 4; j++) {
            int col = n0 + wc * 64 + j * 16 + lr;
            float bv = BIAS ? bias[col] : 0.f;
#pragma unroll
            for (int r = 0; r < 4; r++) {
                float v = acc[i][j][r] + bv;
                if (RES)  v += res[(size_t)(row + r) * N + col];
                if (RELU) v = fmaxf(v, 0.f);
                if (OBF16) ((__bf16*)Cout)[(size_t)(row + r) * N + col] = (__bf16)v;
                else       ((float*)Cout)[(size_t)(row + r) * N + col] = v;
            }
        }
    }
}

// ---------------------------------------------------------------------------
// Fused causal flash attention.
// qkv: bf16 [4096][2304] (q|k|v, each col = h*64+hs). o: bf16 [4096][768].
// Block = (qb, h, b): 64 q-rows, 4 waves x 16 rows. K-blocks of 32 keys.
// K in LDS [32][72] (pad->2-way banks), V transposed [64][40], P via [16][40].
// ---------------------------------------------------------------------------
__global__ __launch_bounds__(256, 2) void attn_kernel(
    const __bf16* __restrict__ qkv, __bf16* __restrict__ o)
{
    __shared__ __bf16 Kl[32][72];
    __shared__ __bf16 Vt[64][40];
    __shared__ __bf16 Pl[4][16][40];
    const int qb = blockIdx.x, h = blockIdx.y, b = blockIdx.z;
    const int tid = threadIdx.x, w = tid >> 6, l = tid & 63, lr = l & 15, lg = l >> 4;
    const int q0 = qb * 64 + w * 16;              // wave's first q row (local to b)
    const size_t rowb = (size_t)b * 1024;

    bf16x8 qf[2];
    {
        const __bf16* qp = qkv + (rowb + q0 + lr) * 2304 + h * 64 + lg * 8;
        qf[0] = *(const bf16x8*)qp;
        qf[1] = *(const bf16x8*)(qp + 32);
    }

    f32x4 oacc[4];
#pragma unroll
    for (int i = 0; i < 4; i++) oacc[i] = (f32x4){0.f, 0.f, 0.f, 0.f};
    float mrow[4] = {-1e30f, -1e30f, -1e30f, -1e30f};
    float lsum[4] = {0.f, 0.f, 0.f, 0.f};

    const int nkb = qb * 2 + 2;                   // keys 0 .. qb*64+63
    const int sk_row = tid >> 3, sk_c = (tid & 7) * 8;
    const int sv_key = tid & 31, sv_h = (tid >> 5) * 8;

    for (int kb = 0; kb < nkb; ++kb) {
        __syncthreads();
        {   // stage K block [32][64] -> Kl
            bf16x8 kv = *(const bf16x8*)(qkv + (rowb + kb * 32 + sk_row) * 2304 + 768 + h * 64 + sk_c);
            *(bf16x8*)&Kl[sk_row][sk_c] = kv;
        }
        {   // stage V block transposed -> Vt[hs][key]
            bf16x8 vv = *(const bf16x8*)(qkv + (rowb + kb * 32 + sv_key) * 2304 + 1536 + h * 64 + sv_h);
#pragma unroll
            for (int j = 0; j < 8; j++) Vt[sv_h + j][sv_key] = vv[j];
        }
        __syncthreads();

        if (kb * 32 <= q0 + 15) {                 // wave has unmasked keys
            float p[2][4];
#pragma unroll
            for (int cb = 0; cb < 2; ++cb) {
                bf16x8 bk0 = *(const bf16x8*)&Kl[cb * 16 + lr][lg * 8];
                bf16x8 bk1 = *(const bf16x8*)&Kl[cb * 16 + lr][32 + lg * 8];
                f32x4 s = (f32x4){0.f, 0.f, 0.f, 0.f};
                s = MFMA16(qf[0], bk0, s);
                s = MFMA16(qf[1], bk1, s);
#pragma unroll
                for (int r = 0; r < 4; r++) {
                    int qrow = q0 + lg * 4 + r;
                    int key  = kb * 32 + cb * 16 + lr;
                    p[cb][r] = (key > qrow) ? -1e30f : s[r] * 0.125f;
                }
            }
#pragma unroll
            for (int r = 0; r < 4; r++) {
                float m2 = fmaxf(p[0][r], p[1][r]);
                m2 = fmaxf(m2, __shfl_xor(m2, 1));
                m2 = fmaxf(m2, __shfl_xor(m2, 2));
                m2 = fmaxf(m2, __shfl_xor(m2, 4));
                m2 = fmaxf(m2, __shfl_xor(m2, 8));
                float mnew  = fmaxf(mrow[r], m2);
                float alpha = __expf(mrow[r] - mnew);
                float p0 = __expf(p[0][r] - mnew);
                float p1 = __expf(p[1][r] - mnew);
                float ps = p0 + p1;
                ps += __shfl_xor(ps, 1);
                ps += __shfl_xor(ps, 2);
                ps += __shfl_xor(ps, 4);
                ps += __shfl_xor(ps, 8);
                lsum[r] = lsum[r] * alpha + ps;
                mrow[r] = mnew;
#pragma unroll
                for (int nb = 0; nb < 4; nb++) oacc[nb][r] *= alpha;
                Pl[w][lg * 4 + r][lr]      = (__bf16)p0;
                Pl[w][lg * 4 + r][16 + lr] = (__bf16)p1;
            }
            // PV: A = P [16 x 32 keys], B = V^T rows
            bf16x8 pf = *(const bf16x8*)&Pl[w][lr][lg * 8];
#pragma unroll
            for (int nb = 0; nb < 4; nb++) {
                bf16x8 vf = *(const bf16x8*)&Vt[nb * 16 + lr][lg * 8];
                oacc[nb] = MFMA16(pf, vf, oacc[nb]);
            }
        }
    }

#pragma unroll
    for (int r = 0; r < 4; r++) {
        float inv = 1.0f / lsum[r];
        size_t row = rowb + q0 + lg * 4 + r;
#pragma unroll
        for (int nb = 0; nb < 4; nb++)
            o[row * 768 + h * 64 + nb * 16 + lr] = (__bf16)(oacc[nb][r] * inv);
    }
}

// ---------------------------------------------------------------------------
extern "C" void kernel_launch(void* const* d_in, const int* in_sizes, int n_in,
                              void* d_out, int out_size, void* d_ws, size_t ws_size,
                              hipStream_t stream)
{
    (void)in_sizes; (void)n_in; (void)out_size; (void)ws_size;
    const int*   idx  = (const int*)d_in[0];
    const float* tok  = (const float*)d_in[1];
    const float* pos  = (const float*)d_in[2];
    const float* Wq   = (const float*)d_in[3];
    const float* Wk   = (const float*)d_in[4];
    const float* Wv   = (const float*)d_in[5];
    const float* Wp   = (const float*)d_in[6];
    const float* bp   = (const float*)d_in[7];
    const float* ln1g = (const float*)d_in[8];
    const float* ln1b = (const float*)d_in[9];
    const float* ln2g = (const float*)d_in[10];
    const float* ln2b = (const float*)d_in[11];
    const float* W1   = (const float*)d_in[12];
    const float* b1   = (const float*)d_in[13];
    const float* W2   = (const float*)d_in[14];
    const float* b2   = (const float*)d_in[15];
    const float* lnfg = (const float*)d_in[16];
    const float* lnfb = (const float*)d_in[17];
    const float* lmW  = (const float*)d_in[18];
    const float* lmb  = (const float*)d_in[19];

    char* ws = (char*)d_ws;
    size_t off = 0;
    auto alloc = [&](size_t bytes) {
        char* p = ws + off;
        off += (bytes + 255) & ~(size_t)255;
        return p;
    };
    __bf16* Wqkv_t = (__bf16*)alloc((size_t)6 * 2304 * 768 * 2);
    __bf16* Wp_t   = (__bf16*)alloc((size_t)6 * 768 * 768 * 2);
    __bf16* W1_t   = (__bf16*)alloc((size_t)6 * 3072 * 768 * 2);
    __bf16* W2_t   = (__bf16*)alloc((size_t)6 * 768 * 3072 * 2);
    __bf16* lm_t   = (__bf16*)alloc((size_t)32000 * 768 * 2);
    float*  x      = (float*)alloc((size_t)4096 * 768 * 4);
    __bf16* hbuf   = (__bf16*)alloc((size_t)4096 * 768 * 2);
    __bf16* qkv    = (__bf16*)alloc((size_t)4096 * 2304 * 2);
    __bf16* obuf   = (__bf16*)alloc((size_t)4096 * 768 * 2);
    __bf16* mlp    = (__bf16*)alloc((size_t)4096 * 3072 * 2);

    // ---- weight repack (bf16, transposed) ----
    transpose_cvt<<<dim3(24 * 24, 6), 256, 0, stream>>>(Wp, Wp_t, 768, 768, 24);
    transpose_cvt<<<dim3(24 * 96, 6), 256, 0, stream>>>(W1, W1_t, 768, 3072, 96);
    transpose_cvt<<<dim3(96 * 24, 6), 256, 0, stream>>>(W2, W2_t, 3072, 768, 24);
    transpose_cvt<<<dim3(24 * 1000, 1), 256, 0, stream>>>(lmW, lm_t, 768, 32000, 1000);
    repack_qkv<<<dim3(48, 36, 6), 256, 0, stream>>>(Wq, Wk, Wv, Wqkv_t);

    // ---- forward ----
    embed_kernel<<<4096, 256, 0, stream>>>(idx, tok, pos, x);

    for (int l = 0; l < 6; l++) {
        ln_kernel<<<4096, 256, 0, stream>>>(x, ln1g + l * 768, ln1b + l * 768, hbuf);
        gemm_bt<0, 0, 0, 1><<<dim3(18, 32), 256, 0, stream>>>(
            hbuf, Wqkv_t + (size_t)l * 2304 * 768, nullptr, nullptr, qkv, 4096, 2304, 768);
        attn_kernel<<<dim3(16, 12, 4), 256, 0, stream>>>(qkv, obuf);
        gemm_bt<0, 1, 1, 0><<<dim3(6, 32), 256, 0, stream>>>(
            obuf, Wp_t + (size_t)l * 768 * 768, bp + l * 768, x, x, 4096, 768, 768);
        ln_kernel<<<4096, 256, 0, stream>>>(x, ln2g + l * 768, ln2b + l * 768, hbuf);
        gemm_bt<1, 1, 0, 1><<<dim3(24, 32), 256, 0, stream>>>(
            hbuf, W1_t + (size_t)l * 3072 * 768, b1 + l * 3072, nullptr, mlp, 4096, 3072, 768);
        gemm_bt<0, 1, 1, 0><<<dim3(6, 32), 256, 0, stream>>>(
            mlp, W2_t + (size_t)l * 768 * 3072, b2 + l * 768, x, x, 4096, 768, 3072);
    }

    ln_kernel<<<4096, 256, 0, stream>>>(x, lnfg, lnfb, hbuf);
    gemm_bt<0, 1, 0, 0><<<dim3(250, 32), 256, 0, stream>>>(
        hbuf, lm_t, lmb, nullptr, d_out, 4096, 32000, 768);
}